// Round 1
// baseline (716.749 us; speedup 1.0000x reference)
//
#include <hip/hip_runtime.h>
#include <hip/hip_bf16.h>
#include <cstdint>

#define WS_    7
#define SHIFT_ 3
#define NH_    8
#define HD_    32
#define C_     256
#define H_     112
#define W_     112
#define B_     8
#define WSQ    49
#define ROWS   100352   // B*H*W == B*nW*49
#define HIDDEN 1024

typedef __attribute__((ext_vector_type(8))) short short8;
typedef __attribute__((ext_vector_type(4))) float f32x4;

__device__ inline ushort f2bf(float f){
  uint32_t u = __float_as_uint(f);
  u += 0x7fffu + ((u >> 16) & 1u);
  return (ushort)(u >> 16);
}
__device__ inline float bf2f(ushort s){ return __uint_as_float(((uint32_t)s) << 16); }

// window-row r -> token index (gather for shifted-window partition; also the
// inverse scatter map for window-reverse + un-shift, which is the same map)
__device__ inline int row2tok(int r){
  int w  = r / WSQ, p = r - w * WSQ;
  int b  = w >> 8, wi = w & 255;
  int wh = wi >> 4, ww = wi & 15;
  int i  = p / WS_, j = p - i * WS_;
  int h  = wh * WS_ + i + SHIFT_; if (h >= H_) h -= H_;
  int wc = ww * WS_ + j + SHIFT_; if (wc >= W_) wc -= W_;
  return b * (H_ * W_) + h * W_ + wc;
}

// ---------------- weight transpose + cast ----------------
__global__ void transpose_cast(const float* __restrict__ in, ushort* __restrict__ out,
                               int K, int N){
  int idx = blockIdx.x * 256 + threadIdx.x;
  if (idx >= K * N) return;
  int k = idx / N, n = idx - k * N;
  out[(size_t)n * K + k] = f2bf(in[idx]);
}

// ---------------- LayerNorm (optionally fused with window gather) ----------------
template<bool GATHER>
__global__ __launch_bounds__(256) void ln_kernel(const float* __restrict__ x,
    const float* __restrict__ g, const float* __restrict__ b, ushort* __restrict__ out)
{
  int wave = threadIdx.x >> 6, lane = threadIdx.x & 63;
  int r = blockIdx.x * 4 + wave;
  int t = GATHER ? row2tok(r) : r;
  const float4 v = *(const float4*)(x + (size_t)t * C_ + lane * 4);
  float s  = v.x + v.y + v.z + v.w;
  float s2 = v.x * v.x + v.y * v.y + v.z * v.z + v.w * v.w;
  #pragma unroll
  for (int m = 32; m; m >>= 1){ s += __shfl_xor(s, m); s2 += __shfl_xor(s2, m); }
  float mean = s * (1.f / C_);
  float inv  = rsqrtf(fmaxf(s2 * (1.f / C_) - mean * mean, 0.f) + 1e-5f);
  int c0 = lane * 4;
  ushort4 o;
  o.x = f2bf((v.x - mean) * inv * g[c0 + 0] + b[c0 + 0]);
  o.y = f2bf((v.y - mean) * inv * g[c0 + 1] + b[c0 + 1]);
  o.z = f2bf((v.z - mean) * inv * g[c0 + 2] + b[c0 + 2]);
  o.w = f2bf((v.w - mean) * inv * g[c0 + 3] + b[c0 + 3]);
  *(ushort4*)(out + (size_t)r * C_ + c0) = o;
}

// ---------------- 128x128x32 bf16 MFMA GEMM (m97 structure) ----------------
__device__ inline void gll16(const void* g, void* l){
  __builtin_amdgcn_global_load_lds(
      (__attribute__((address_space(1))) void*)g,
      (__attribute__((address_space(3))) void*)l, 16, 0, 0);
}

// EPI: 0 = +bias -> bf16 (qkv)
//      1 = +bias + window-reverse scatter + residual(x, token order) -> f32
//      2 = +bias + exact GELU -> bf16
//      3 = +bias + residual(row order) -> f32
template<int EPI>
__global__ __launch_bounds__(256, 2) void gemm128(
    const ushort* __restrict__ A,   // M x K row-major bf16
    const ushort* __restrict__ Bt,  // N x K row-major bf16 (transposed weight)
    const float*  __restrict__ bias,
    void*         __restrict__ Cout,
    const float*  __restrict__ resid,
    int M, int N, int K)
{
  __shared__ __align__(16) ushort lA[128 * 32];
  __shared__ __align__(16) ushort lB[128 * 32];
  const int tid  = threadIdx.x;
  const int m0   = blockIdx.x * 128, n0 = blockIdx.y * 128;
  const int wave = tid >> 6, lane = tid & 63;
  const int wr   = wave >> 1, wc = wave & 1;
  const int la   = lane & 15, lg = lane >> 4;

  f32x4 acc[4][4] = {};

  const int r0 = tid >> 2, kp = (tid & 3) * 8;
  const ushort* pA0 = A  + (size_t)(m0 + r0)      * K + kp;
  const ushort* pA1 = A  + (size_t)(m0 + r0 + 64) * K + kp;
  const ushort* pB0 = Bt + (size_t)(n0 + r0)      * K + kp;
  const ushort* pB1 = Bt + (size_t)(n0 + r0 + 64) * K + kp;
  ushort* lA0 = lA + tid * 8;  ushort* lA1 = lA + (tid + 256) * 8;
  ushort* lB0 = lB + tid * 8;  ushort* lB1 = lB + (tid + 256) * 8;

  for (int k0 = 0; k0 < K; k0 += 32){
    gll16(pA0 + k0, lA0);
    gll16(pA1 + k0, lA1);
    gll16(pB0 + k0, lB0);
    gll16(pB1 + k0, lB1);
    __syncthreads();
    short8 af[4], bfr[4];
    #pragma unroll
    for (int i = 0; i < 4; i++) af[i]  = *(const short8*)&lA[(wr * 64 + i * 16 + la) * 32 + lg * 8];
    #pragma unroll
    for (int j = 0; j < 4; j++) bfr[j] = *(const short8*)&lB[(wc * 64 + j * 16 + la) * 32 + lg * 8];
    #pragma unroll
    for (int i = 0; i < 4; i++)
      #pragma unroll
      for (int j = 0; j < 4; j++)
        acc[i][j] = __builtin_amdgcn_mfma_f32_16x16x32_bf16(af[i], bfr[j], acc[i][j], 0, 0, 0);
    __syncthreads();
  }

  #pragma unroll
  for (int i = 0; i < 4; i++){
    #pragma unroll
    for (int j = 0; j < 4; j++){
      int col = n0 + wc * 64 + j * 16 + la;
      float bs = bias[col];
      #pragma unroll
      for (int q = 0; q < 4; q++){
        int row = m0 + wr * 64 + i * 16 + lg * 4 + q;
        float v = acc[i][j][q] + bs;
        if (EPI == 0){
          ((ushort*)Cout)[(size_t)row * N + col] = f2bf(v);
        } else if (EPI == 1){
          int t = row2tok(row);
          size_t o = (size_t)t * C_ + col;
          ((float*)Cout)[o] = resid[o] + v;
        } else if (EPI == 2){
          float gx = 0.5f * v * (1.f + erff(v * 0.70710678118f));
          ((ushort*)Cout)[(size_t)row * N + col] = f2bf(gx);
        } else {
          size_t o = (size_t)row * C_ + col;
          ((float*)Cout)[o] = resid[o] + v;
        }
      }
    }
  }
}

// ---------------- windowed attention: one wave per (window, head) ----------------
__global__ __launch_bounds__(256, 2) void attn_kernel(const ushort* __restrict__ qkv,
    const float* __restrict__ mask, ushort* __restrict__ out)
{
  __shared__ __align__(16) ushort P [4][64 * 72];
  __shared__ __align__(16) ushort VT[4][32 * 72];
  const int wave = threadIdx.x >> 6, lane = threadIdx.x & 63;
  const int gid  = blockIdx.x * 4 + wave;
  const int w    = gid >> 3, head = gid & 7;
  const int la   = lane & 15, lg = lane >> 4;
  const ushort* qb = qkv + (size_t)w * WSQ * 768 + head * HD_;
  const short8 z8 = {0,0,0,0,0,0,0,0};

  // zero V^T (incl. key-pad rows), then fill transposed
  {
    ushort4 z4 = {0,0,0,0};
    for (int idx = lane; idx < (32 * 72) / 4; idx += 64) ((ushort4*)VT[wave])[idx] = z4;
    for (int idx = lane; idx < WSQ * 4; idx += 64){
      int row = idx >> 2, db = idx & 3;
      short8 vv = *(const short8*)&qb[(size_t)row * 768 + 512 + db * 8];
      #pragma unroll
      for (int e = 0; e < 8; e++) VT[wave][(db * 8 + e) * 72 + row] = ((ushort*)&vv)[e];
    }
  }

  // Q / K fragments (rows >= 49 zero-padded)
  short8 qf[4], kf[4];
  #pragma unroll
  for (int i = 0; i < 4; i++){
    int m = i * 16 + la;
    qf[i] = (m < WSQ) ? *(const short8*)&qb[(size_t)m * 768 +       lg * 8] : z8;
    kf[i] = (m < WSQ) ? *(const short8*)&qb[(size_t)m * 768 + 256 + lg * 8] : z8;
  }

  f32x4 s[4][4] = {};
  #pragma unroll
  for (int i = 0; i < 4; i++)
    #pragma unroll
    for (int j = 0; j < 4; j++)
      s[i][j] = __builtin_amdgcn_mfma_f32_16x16x32_bf16(qf[i], kf[j], s[i][j], 0, 0, 0);

  // masked, scaled softmax; unnormalized exp -> P (bf16), 1/sum kept per-lane
  const float* mrow = mask + (size_t)(w & 255) * WSQ * WSQ;
  const float scale = 0.17677669529663687f;   // 32^-0.5
  float rinv[4][4];
  #pragma unroll
  for (int i = 0; i < 4; i++){
    #pragma unroll
    for (int q = 0; q < 4; q++){
      int m = i * 16 + lg * 4 + q;
      float pv[4]; float mx = -1e30f;
      #pragma unroll
      for (int j = 0; j < 4; j++){
        int n = j * 16 + la;
        float val = (m < WSQ && n < WSQ) ? s[i][j][q] * scale + mrow[m * WSQ + n] : -1e30f;
        pv[j] = val; mx = fmaxf(mx, val);
      }
      #pragma unroll
      for (int msk = 1; msk < 16; msk <<= 1) mx = fmaxf(mx, __shfl_xor(mx, msk));
      float sum = 0.f;
      #pragma unroll
      for (int j = 0; j < 4; j++){ float e = __expf(pv[j] - mx); pv[j] = e; sum += e; }
      #pragma unroll
      for (int msk = 1; msk < 16; msk <<= 1) sum += __shfl_xor(sum, msk);
      rinv[i][q] = 1.f / sum;
      #pragma unroll
      for (int j = 0; j < 4; j++) P[wave][m * 72 + j * 16 + la] = f2bf(pv[j]);
    }
  }

  // O = P @ V  (K split into two 32-chunks; padded keys have P==0 / V==0)
  f32x4 o[4][2] = {};
  #pragma unroll
  for (int kk = 0; kk < 2; kk++){
    short8 pf[4], vf[2];
    #pragma unroll
    for (int i = 0; i < 4; i++)  pf[i]  = *(const short8*)&P [wave][(i  * 16 + la) * 72 + kk * 32 + lg * 8];
    #pragma unroll
    for (int jn = 0; jn < 2; jn++) vf[jn] = *(const short8*)&VT[wave][(jn * 16 + la) * 72 + kk * 32 + lg * 8];
    #pragma unroll
    for (int i = 0; i < 4; i++)
      #pragma unroll
      for (int jn = 0; jn < 2; jn++)
        o[i][jn] = __builtin_amdgcn_mfma_f32_16x16x32_bf16(pf[i], vf[jn], o[i][jn], 0, 0, 0);
  }

  ushort* ob = out + (size_t)w * WSQ * C_ + head * HD_;
  #pragma unroll
  for (int i = 0; i < 4; i++)
    #pragma unroll
    for (int jn = 0; jn < 2; jn++)
      #pragma unroll
      for (int q = 0; q < 4; q++){
        int m = i * 16 + lg * 4 + q;
        if (m < WSQ) ob[(size_t)m * C_ + jn * 16 + la] = f2bf(o[i][jn][q] * rinv[i][q]);
      }
}

// ---------------- launch ----------------
extern "C" void kernel_launch(void* const* d_in, const int* in_sizes, int n_in,
                              void* d_out, int out_size, void* d_ws, size_t ws_size,
                              hipStream_t stream)
{
  const float* x      = (const float*)d_in[0];
  const float* mask   = (const float*)d_in[1];
  const float* n1g    = (const float*)d_in[2];
  const float* n1b    = (const float*)d_in[3];
  const float* qkv_w  = (const float*)d_in[4];
  const float* qkv_b  = (const float*)d_in[5];
  const float* proj_w = (const float*)d_in[6];
  const float* proj_b = (const float*)d_in[7];
  const float* n2g    = (const float*)d_in[8];
  const float* n2b    = (const float*)d_in[9];
  const float* fc1_w  = (const float*)d_in[10];
  const float* fc1_b  = (const float*)d_in[11];
  const float* fc2_w  = (const float*)d_in[12];
  const float* fc2_b  = (const float*)d_in[13];

  char* ws = (char*)d_ws;
  // R1: 100352*256 bf16  (xw -> attn_out -> h)
  // R2: 100352*1024 bf16 (qkv [uses 768 cols] -> gelu out)
  // R3: 100352*256 f32   (x2 = post-attn residual)
  // R4: transposed bf16 weights
  ushort* R1 = (ushort*)ws;
  ushort* R2 = (ushort*)(ws + 51380224);
  float*  x2 = (float*) (ws + 51380224 + 205520896);
  ushort* wqT = (ushort*)(ws + 51380224 + 205520896 + 102760448);
  ushort* wpT = wqT + 768 * 256;
  ushort* w1T = wpT + 256 * 256;
  ushort* w2T = w1T + 1024 * 256;

  transpose_cast<<<(256 * 768  + 255) / 256, 256, 0, stream>>>(qkv_w,  wqT, 256, 768);
  transpose_cast<<<(256 * 256  + 255) / 256, 256, 0, stream>>>(proj_w, wpT, 256, 256);
  transpose_cast<<<(256 * 1024 + 255) / 256, 256, 0, stream>>>(fc1_w,  w1T, 256, 1024);
  transpose_cast<<<(1024 * 256 + 255) / 256, 256, 0, stream>>>(fc2_w,  w2T, 1024, 256);

  ln_kernel<true><<<ROWS / 4, 256, 0, stream>>>(x, n1g, n1b, R1);
  gemm128<0><<<dim3(ROWS / 128, 6), 256, 0, stream>>>(R1, wqT, qkv_b, R2, nullptr, ROWS, 768, 256);
  attn_kernel<<<(2048 * 8) / 4, 256, 0, stream>>>(R2, mask, R1);
  gemm128<1><<<dim3(ROWS / 128, 2), 256, 0, stream>>>(R1, wpT, proj_b, x2, x, ROWS, 256, 256);
  ln_kernel<false><<<ROWS / 4, 256, 0, stream>>>(x2, n2g, n2b, R1);
  gemm128<2><<<dim3(ROWS / 128, 8), 256, 0, stream>>>(R1, w1T, fc1_b, R2, nullptr, ROWS, 1024, 256);
  gemm128<3><<<dim3(ROWS / 128, 2), 256, 0, stream>>>(R2, w2T, fc2_b, d_out, x2, ROWS, 256, 1024);
}

// Round 2
// 674.447 us; speedup vs baseline: 1.0627x; 1.0627x over previous
//
#include <hip/hip_runtime.h>
#include <hip/hip_bf16.h>
#include <cstdint>

#define WS_    7
#define SHIFT_ 3
#define NH_    8
#define HD_    32
#define C_     256
#define H_     112
#define W_     112
#define B_     8
#define WSQ    49
#define ROWS   100352   // B*H*W == B*nW*49
#define HIDDEN 1024

typedef __attribute__((ext_vector_type(8))) short short8;
typedef __attribute__((ext_vector_type(4))) float f32x4;

__device__ inline ushort f2bf(float f){
  uint32_t u = __float_as_uint(f);
  u += 0x7fffu + ((u >> 16) & 1u);
  return (ushort)(u >> 16);
}

// window-row r -> token index (gather for shifted-window partition; also the
// inverse scatter map for window-reverse + un-shift, which is the same map)
__device__ inline int row2tok(int r){
  int w  = r / WSQ, p = r - w * WSQ;
  int b  = w >> 8, wi = w & 255;
  int wh = wi >> 4, ww = wi & 15;
  int i  = p / WS_, j = p - i * WS_;
  int h  = wh * WS_ + i + SHIFT_; if (h >= H_) h -= H_;
  int wc = ww * WS_ + j + SHIFT_; if (wc >= W_) wc -= W_;
  return b * (H_ * W_) + h * W_ + wc;
}

// ---------------- weight transpose + cast ----------------
__global__ void transpose_cast(const float* __restrict__ in, ushort* __restrict__ out,
                               int K, int N){
  int idx = blockIdx.x * 256 + threadIdx.x;
  if (idx >= K * N) return;
  int k = idx / N, n = idx - k * N;
  out[(size_t)n * K + k] = f2bf(in[idx]);
}

// ---------------- LayerNorm (optionally fused with window gather) ----------------
template<bool GATHER>
__global__ __launch_bounds__(256) void ln_kernel(const float* __restrict__ x,
    const float* __restrict__ g, const float* __restrict__ b, ushort* __restrict__ out)
{
  int wave = threadIdx.x >> 6, lane = threadIdx.x & 63;
  int r = blockIdx.x * 4 + wave;
  int t = GATHER ? row2tok(r) : r;
  const float4 v = *(const float4*)(x + (size_t)t * C_ + lane * 4);
  float s  = v.x + v.y + v.z + v.w;
  float s2 = v.x * v.x + v.y * v.y + v.z * v.z + v.w * v.w;
  #pragma unroll
  for (int m = 32; m; m >>= 1){ s += __shfl_xor(s, m); s2 += __shfl_xor(s2, m); }
  float mean = s * (1.f / C_);
  float inv  = rsqrtf(fmaxf(s2 * (1.f / C_) - mean * mean, 0.f) + 1e-5f);
  int c0 = lane * 4;
  ushort4 o;
  o.x = f2bf((v.x - mean) * inv * g[c0 + 0] + b[c0 + 0]);
  o.y = f2bf((v.y - mean) * inv * g[c0 + 1] + b[c0 + 1]);
  o.z = f2bf((v.z - mean) * inv * g[c0 + 2] + b[c0 + 2]);
  o.w = f2bf((v.w - mean) * inv * g[c0 + 3] + b[c0 + 3]);
  *(ushort4*)(out + (size_t)r * C_ + c0) = o;
}

// ---------------- 128x256 bf16 MFMA GEMM, 8 waves, dbuf LDS, XCD swizzle ----------------
__device__ inline void gll16(const void* g, void* l){
  __builtin_amdgcn_global_load_lds(
      (__attribute__((address_space(1))) void*)g,
      (__attribute__((address_space(3))) void*)l, 16, 0, 0);
}

// EPI: 0 = +bias -> bf16 (qkv)
//      1 = +bias + window-reverse scatter + residual(x, token order) -> f32
//      2 = +bias + exact GELU -> bf16
//      3 = +bias + residual(row order) -> f32
template<int EPI>
__global__ __launch_bounds__(512, 4) void gemmW(
    const ushort* __restrict__ A,   // M x K row-major bf16
    const ushort* __restrict__ Bt,  // N x K row-major bf16 (transposed weight)
    const float*  __restrict__ bias,
    void*         __restrict__ Cout,
    const float*  __restrict__ resid,
    int M, int N, int K, int nN)    // nN = N / 256 column-blocks
{
  __shared__ __align__(16) ushort lA[2][128 * 32];
  __shared__ __align__(16) ushort lB[2][256 * 32];
  const int tid  = threadIdx.x;

  // bijective XCD swizzle (gridDim.x % 8 == 0 here: M/128 = 784 = 8*98).
  // consecutive lids (same XCD) share the same A row-tile -> A fetched once.
  const int cpx  = gridDim.x >> 3;
  const int lid  = (blockIdx.x & 7) * cpx + (blockIdx.x >> 3);
  const int rowb = lid / nN, colb = lid - rowb * nN;
  const int m0   = rowb * 128, n0 = colb * 256;

  const int wave = tid >> 6, lane = tid & 63;
  const int wr   = wave >> 2, wc = wave & 3;    // 2 x 4 wave grid, 64x64 each
  const int la   = lane & 15, lg = lane >> 4;

  f32x4 acc[4][4] = {};

  const int r0 = tid >> 2, kp = (tid & 3) * 8;
  const ushort* gA  = A  + (size_t)(m0 + r0)       * K + kp;
  const ushort* gB0 = Bt + (size_t)(n0 + r0)       * K + kp;
  const ushort* gB1 = Bt + (size_t)(n0 + r0 + 128) * K + kp;

  const int nt = K >> 5;
  int buf = 0;

  // prologue stage
  gll16(gA,  &lA[0][tid * 8]);
  gll16(gB0, &lB[0][tid * 8]);
  gll16(gB1, &lB[0][(tid + 512) * 8]);
  __syncthreads();

  for (int t = 0; t < nt; ++t){
    if (t + 1 < nt){
      const int k0 = (t + 1) * 32;
      gll16(gA  + k0, &lA[buf ^ 1][tid * 8]);
      gll16(gB0 + k0, &lB[buf ^ 1][tid * 8]);
      gll16(gB1 + k0, &lB[buf ^ 1][(tid + 512) * 8]);
    }
    short8 af[4], bfr[4];
    #pragma unroll
    for (int i = 0; i < 4; i++) af[i]  = *(const short8*)&lA[buf][(wr * 64 + i * 16 + la) * 32 + lg * 8];
    #pragma unroll
    for (int j = 0; j < 4; j++) bfr[j] = *(const short8*)&lB[buf][(wc * 64 + j * 16 + la) * 32 + lg * 8];
    #pragma unroll
    for (int i = 0; i < 4; i++)
      #pragma unroll
      for (int j = 0; j < 4; j++)
        acc[i][j] = __builtin_amdgcn_mfma_f32_16x16x32_bf16(af[i], bfr[j], acc[i][j], 0, 0, 0);
    __syncthreads();   // drains vmcnt(0): next buffer staged; this buffer free to overwrite
    buf ^= 1;
  }

  #pragma unroll
  for (int i = 0; i < 4; i++){
    #pragma unroll
    for (int j = 0; j < 4; j++){
      int col = n0 + wc * 64 + j * 16 + la;
      float bs = bias[col];
      #pragma unroll
      for (int q = 0; q < 4; q++){
        int row = m0 + wr * 64 + i * 16 + lg * 4 + q;
        float v = acc[i][j][q] + bs;
        if (EPI == 0){
          ((ushort*)Cout)[(size_t)row * N + col] = f2bf(v);
        } else if (EPI == 1){
          int t = row2tok(row);
          size_t o = (size_t)t * C_ + col;
          ((float*)Cout)[o] = resid[o] + v;
        } else if (EPI == 2){
          float gx = 0.5f * v * (1.f + erff(v * 0.70710678118f));
          ((ushort*)Cout)[(size_t)row * N + col] = f2bf(gx);
        } else {
          size_t o = (size_t)row * C_ + col;
          ((float*)Cout)[o] = resid[o] + v;
        }
      }
    }
  }
}

// ---------------- windowed attention: one wave per (window, head) ----------------
__global__ __launch_bounds__(256, 2) void attn_kernel(const ushort* __restrict__ qkv,
    const float* __restrict__ mask, ushort* __restrict__ out)
{
  __shared__ __align__(16) ushort P [4][64 * 72];
  __shared__ __align__(16) ushort VT[4][32 * 72];
  const int wave = threadIdx.x >> 6, lane = threadIdx.x & 63;
  const int gid  = blockIdx.x * 4 + wave;
  const int w    = gid >> 3, head = gid & 7;
  const int la   = lane & 15, lg = lane >> 4;
  const ushort* qb = qkv + (size_t)w * WSQ * 768 + head * HD_;
  const short8 z8 = {0,0,0,0,0,0,0,0};

  // zero V^T (incl. key-pad rows), then fill transposed
  {
    ushort4 z4 = {0,0,0,0};
    for (int idx = lane; idx < (32 * 72) / 4; idx += 64) ((ushort4*)VT[wave])[idx] = z4;
    for (int idx = lane; idx < WSQ * 4; idx += 64){
      int row = idx >> 2, db = idx & 3;
      short8 vv = *(const short8*)&qb[(size_t)row * 768 + 512 + db * 8];
      #pragma unroll
      for (int e = 0; e < 8; e++) VT[wave][(db * 8 + e) * 72 + row] = ((ushort*)&vv)[e];
    }
  }

  // Q / K fragments (rows >= 49 zero-padded)
  short8 qf[4], kf[4];
  #pragma unroll
  for (int i = 0; i < 4; i++){
    int m = i * 16 + la;
    qf[i] = (m < WSQ) ? *(const short8*)&qb[(size_t)m * 768 +       lg * 8] : z8;
    kf[i] = (m < WSQ) ? *(const short8*)&qb[(size_t)m * 768 + 256 + lg * 8] : z8;
  }

  f32x4 s[4][4] = {};
  #pragma unroll
  for (int i = 0; i < 4; i++)
    #pragma unroll
    for (int j = 0; j < 4; j++)
      s[i][j] = __builtin_amdgcn_mfma_f32_16x16x32_bf16(qf[i], kf[j], s[i][j], 0, 0, 0);

  // masked, scaled softmax; unnormalized exp -> P (bf16), 1/sum kept per-lane
  const float* mrow = mask + (size_t)(w & 255) * WSQ * WSQ;
  const float scale = 0.17677669529663687f;   // 32^-0.5
  float rinv[4][4];
  #pragma unroll
  for (int i = 0; i < 4; i++){
    #pragma unroll
    for (int q = 0; q < 4; q++){
      int m = i * 16 + lg * 4 + q;
      float pv[4]; float mx = -1e30f;
      #pragma unroll
      for (int j = 0; j < 4; j++){
        int n = j * 16 + la;
        float val = (m < WSQ && n < WSQ) ? s[i][j][q] * scale + mrow[m * WSQ + n] : -1e30f;
        pv[j] = val; mx = fmaxf(mx, val);
      }
      #pragma unroll
      for (int msk = 1; msk < 16; msk <<= 1) mx = fmaxf(mx, __shfl_xor(mx, msk));
      float sum = 0.f;
      #pragma unroll
      for (int j = 0; j < 4; j++){ float e = __expf(pv[j] - mx); pv[j] = e; sum += e; }
      #pragma unroll
      for (int msk = 1; msk < 16; msk <<= 1) sum += __shfl_xor(sum, msk);
      rinv[i][q] = 1.f / sum;
      #pragma unroll
      for (int j = 0; j < 4; j++) P[wave][m * 72 + j * 16 + la] = f2bf(pv[j]);
    }
  }

  // O = P @ V  (K split into two 32-chunks; padded keys have P==0 / V==0)
  f32x4 o[4][2] = {};
  #pragma unroll
  for (int kk = 0; kk < 2; kk++){
    short8 pf[4], vf[2];
    #pragma unroll
    for (int i = 0; i < 4; i++)  pf[i]  = *(const short8*)&P [wave][(i  * 16 + la) * 72 + kk * 32 + lg * 8];
    #pragma unroll
    for (int jn = 0; jn < 2; jn++) vf[jn] = *(const short8*)&VT[wave][(jn * 16 + la) * 72 + kk * 32 + lg * 8];
    #pragma unroll
    for (int i = 0; i < 4; i++)
      #pragma unroll
      for (int jn = 0; jn < 2; jn++)
        o[i][jn] = __builtin_amdgcn_mfma_f32_16x16x32_bf16(pf[i], vf[jn], o[i][jn], 0, 0, 0);
  }

  ushort* ob = out + (size_t)w * WSQ * C_ + head * HD_;
  #pragma unroll
  for (int i = 0; i < 4; i++)
    #pragma unroll
    for (int jn = 0; jn < 2; jn++)
      #pragma unroll
      for (int q = 0; q < 4; q++){
        int m = i * 16 + lg * 4 + q;
        if (m < WSQ) ob[(size_t)m * C_ + jn * 16 + la] = f2bf(o[i][jn][q] * rinv[i][q]);
      }
}

// ---------------- launch ----------------
extern "C" void kernel_launch(void* const* d_in, const int* in_sizes, int n_in,
                              void* d_out, int out_size, void* d_ws, size_t ws_size,
                              hipStream_t stream)
{
  const float* x      = (const float*)d_in[0];
  const float* mask   = (const float*)d_in[1];
  const float* n1g    = (const float*)d_in[2];
  const float* n1b    = (const float*)d_in[3];
  const float* qkv_w  = (const float*)d_in[4];
  const float* qkv_b  = (const float*)d_in[5];
  const float* proj_w = (const float*)d_in[6];
  const float* proj_b = (const float*)d_in[7];
  const float* n2g    = (const float*)d_in[8];
  const float* n2b    = (const float*)d_in[9];
  const float* fc1_w  = (const float*)d_in[10];
  const float* fc1_b  = (const float*)d_in[11];
  const float* fc2_w  = (const float*)d_in[12];
  const float* fc2_b  = (const float*)d_in[13];

  char* ws = (char*)d_ws;
  // R1: 100352*256 bf16  (xw -> attn_out -> h)
  // R2: 100352*1024 bf16 (qkv [uses 768 cols] -> gelu out)
  // x2: 100352*256 f32   (post-attn residual)
  // then transposed bf16 weights
  ushort* R1 = (ushort*)ws;
  ushort* R2 = (ushort*)(ws + 51380224);
  float*  x2 = (float*) (ws + 51380224 + 205520896);
  ushort* wqT = (ushort*)(ws + 51380224 + 205520896 + 102760448);
  ushort* wpT = wqT + 768 * 256;
  ushort* w1T = wpT + 256 * 256;
  ushort* w2T = w1T + 1024 * 256;

  transpose_cast<<<(256 * 768  + 255) / 256, 256, 0, stream>>>(qkv_w,  wqT, 256, 768);
  transpose_cast<<<(256 * 256  + 255) / 256, 256, 0, stream>>>(proj_w, wpT, 256, 256);
  transpose_cast<<<(256 * 1024 + 255) / 256, 256, 0, stream>>>(fc1_w,  w1T, 256, 1024);
  transpose_cast<<<(1024 * 256 + 255) / 256, 256, 0, stream>>>(fc2_w,  w2T, 1024, 256);

  ln_kernel<true><<<ROWS / 4, 256, 0, stream>>>(x, n1g, n1b, R1);
  gemmW<0><<<784 * 3, 512, 0, stream>>>(R1, wqT, qkv_b, R2, nullptr, ROWS, 768, 256, 3);
  attn_kernel<<<(2048 * 8) / 4, 256, 0, stream>>>(R2, mask, R1);
  gemmW<1><<<784 * 1, 512, 0, stream>>>(R1, wpT, proj_b, x2, x, ROWS, 256, 256, 1);
  ln_kernel<false><<<ROWS / 4, 256, 0, stream>>>(x2, n2g, n2b, R1);
  gemmW<2><<<784 * 4, 512, 0, stream>>>(R1, w1T, fc1_b, R2, nullptr, ROWS, 1024, 256, 4);
  gemmW<3><<<784 * 1, 512, 0, stream>>>(R2, w2T, fc2_b, d_out, x2, ROWS, 256, 1024, 1);
}